// Round 17
// baseline (385.589 us; speedup 1.0000x reference)
//
#include <hip/hip_runtime.h>
#include <hip/hip_bf16.h>

typedef __attribute__((ext_vector_type(8))) short short8;   // 8 bf16 (4 VGPR)
typedef __attribute__((ext_vector_type(4))) float f32x4;
typedef __attribute__((ext_vector_type(2))) unsigned int u32x2;

constexpr int D_DIM = 512;
constexpr int S_DIM = 2048;

static __device__ __forceinline__ unsigned short f2bf(float f) {
  __hip_bfloat16 h = __float2bfloat16(f);
  return *reinterpret_cast<unsigned short*>(&h);
}

#define GLP(p) ((const __attribute__((address_space(1))) unsigned int*)(p))
#define LDP(p) ((__attribute__((address_space(3))) unsigned int*)(p))

static __device__ __forceinline__ void blockbar() {
  asm volatile("" ::: "memory");
  __builtin_amdgcn_s_barrier();
  asm volatile("" ::: "memory");
}

// ---- setup: L2-normalize rows -> bf16 [rows][512], one wave per row ----
// Optionally zero-init rowsum[row] (folds the memset into this pass).
__global__ void k_norm(const float* __restrict__ K, ushort* __restrict__ Kn,
                       float* __restrict__ rowsum) {
  const int row = blockIdx.x * 4 + (threadIdx.x >> 6);
  const int l   = threadIdx.x & 63;
  const float* src = K + (size_t)row * D_DIM + l * 8;
  float4 v0 = *(const float4*)(src);
  float4 v1 = *(const float4*)(src + 4);
  float ss = v0.x*v0.x + v0.y*v0.y + v0.z*v0.z + v0.w*v0.w
           + v1.x*v1.x + v1.y*v1.y + v1.z*v1.z + v1.w*v1.w;
  #pragma unroll
  for (int off = 1; off < 64; off <<= 1) ss += __shfl_xor(ss, off, 64);
  const float sc = 1.0f / fmaxf(sqrtf(ss), 1e-12f);
  float f[8] = {v0.x,v0.y,v0.z,v0.w,v1.x,v1.y,v1.z,v1.w};
  unsigned uu[4];
  #pragma unroll
  for (int i = 0; i < 4; ++i)
    uu[i] = (unsigned)f2bf(f[2*i]*sc) | ((unsigned)f2bf(f[2*i+1]*sc) << 16);
  *(uint4*)(Kn + (size_t)row * D_DIM + l*8) = make_uint4(uu[0],uu[1],uu[2],uu[3]);
  if (rowsum != nullptr && l == 0) rowsum[row] = 0.f;
}

// ---- setup: transpose V[S][D] f32 -> Vt[D][S] bf16 ----
__global__ void k_transpose_v(const float* __restrict__ V, ushort* __restrict__ Vt) {
  __shared__ float tile[64][65];
  const int s0 = blockIdx.x * 64;
  const int d0 = blockIdx.y * 64;
  const int tj = threadIdx.x & 63;
  const int ti = threadIdx.x >> 6;
  #pragma unroll
  for (int k = 0; k < 16; ++k) {
    int s = ti + 4*k;
    tile[s][tj] = V[(size_t)(s0+s) * D_DIM + d0 + tj];
  }
  __syncthreads();
  #pragma unroll
  for (int k = 0; k < 16; ++k) {
    int d = ti + 4*k;
    Vt[(size_t)(d0+d) * S_DIM + s0 + tj] = f2bf(tile[tj][d]);
  }
}

// ===== GEMM1: 128x256, 2-phase, triple-buffered (R13 gemm2_bt structure) =====
// C = exp(A*B^T) -> bf16 Pout + atomic rowsum. 8 waves (2M x 4N), wave C=64x64.
// LDS: 3 buf x 3 slots (A0,B0,B1) x 16KB = 144KB. Tile t+2 staged during t
// (ph1: A0,B0; ph2: B1); 6 loads/tile; vmcnt(6) steady, vmcnt(0) last tile.
__global__ __launch_bounds__(512, 2) void gemm1_bt(
    const ushort* __restrict__ A, const ushort* __restrict__ B,
    int aStride, int bStride,      // row strides in BYTES
    int NT,                        // K / 64
    ushort* __restrict__ Pout, float* __restrict__ rowsum,
    int ldC)
{
  __shared__ ushort lds[3][3][8192];   // [buf][slot:A0,B0,B1][16KB] = 144KB
  char* ldsb = (char*)&lds[0][0][0];

  const int tid = threadIdx.x;
  const int w   = tid >> 6;
  const int l   = tid & 63;
  const int lhi = l >> 4;
  const int llo = l & 15;
  const int wm  = w >> 2;        // 0..1
  const int wn  = w & 3;         // 0..3
  const size_t m0 = (size_t)blockIdx.x * 128;
  const size_t n0 = (size_t)blockIdx.y * 256;

  const char* Ab = (const char*)A;
  const char* Bb = (const char*)B;

  const int srow = tid >> 3;           // 0..63
  const int scb  = (tid & 7) * 16;     // 0..112
  const char* gp[3][2];
  #pragma unroll
  for (int slot = 0; slot < 3; ++slot) {
    const char* src; int stride; size_t r0;
    if (slot == 0) { src = Ab; stride = aStride; r0 = m0; }
    else           { src = Bb; stride = bStride; r0 = n0 + (size_t)(slot - 1) * 128; }
    const unsigned sw = (unsigned)(scb ^ ((srow & 7) << 4));
    gp[slot][0] = src + (r0 + srow) * (size_t)stride + sw;
    gp[slot][1] = src + (r0 + srow + 64) * (size_t)stride + sw;
  }
  auto stage = [&](int buf, int slot, int t) {
    char* lbase = ldsb + ((buf*3 + slot) * 16384) + w * 1024;   // wave-uniform
    const int toff = t * 128;
    __builtin_amdgcn_global_load_lds(GLP(gp[slot][0] + toff), LDP(lbase), 16, 0, 0);
    __builtin_amdgcn_global_load_lds(GLP(gp[slot][1] + toff), LDP(lbase + 8192), 16, 0, 0);
  };

  const unsigned swz = (unsigned)((l & 7) << 4);
  short8 ar[4][2], br01[2][2], br23[2][2];
  f32x4 acc[4][4] = {};

  const unsigned aRow0 = (unsigned)(wm * 64);
  const int bSlot = 1 + (wn >> 1);
  const unsigned bRow0 = (unsigned)((wn & 1) * 64);

  auto readA = [&](int buf) {
    const char* base = ldsb + (buf*3) * 16384;
    #pragma unroll
    for (int rf = 0; rf < 4; ++rf)
      #pragma unroll
      for (int kk = 0; kk < 2; ++kk) {
        unsigned off = (unsigned)((aRow0 + rf*16 + llo) * 128)
                     + (((unsigned)(kk*64 + lhi*16)) ^ swz);
        ar[rf][kk] = *(const short8*)(base + off);
      }
  };
  auto readB = [&](int buf, int cfB, short8 (&br)[2][2]) {
    const char* base = ldsb + (buf*3 + bSlot) * 16384;
    #pragma unroll
    for (int c = 0; c < 2; ++c)
      #pragma unroll
      for (int kk = 0; kk < 2; ++kk) {
        unsigned off = (unsigned)((bRow0 + (cfB + c) * 16 + llo) * 128)
                     + (((unsigned)(kk*64 + lhi*16)) ^ swz);
        br[c][kk] = *(const short8*)(base + off);
      }
  };
  auto quad = [&](int cfB, short8 (&br)[2][2]) {
    __builtin_amdgcn_s_setprio(1);
    #pragma unroll
    for (int kk = 0; kk < 2; ++kk)
      #pragma unroll
      for (int rf = 0; rf < 4; ++rf)
        #pragma unroll
        for (int c = 0; c < 2; ++c)
          acc[rf][cfB+c] = __builtin_amdgcn_mfma_f32_16x16x32_bf16(
              ar[rf][kk], br[c][kk], acc[rf][cfB+c], 0, 0, 0);
    __builtin_amdgcn_s_setprio(0);
  };

  // prologue: tiles 0 and 1 (buffers 0, 1)
  stage(0, 0, 0); stage(0, 1, 0); stage(0, 2, 0);
  stage(1, 0, 1); stage(1, 1, 1); stage(1, 2, 1);

  for (int t = 0; t < NT; ++t) {
    const int cur = t % 3, nx2 = (t + 2) % 3;
    // ph1
    if (t + 1 < NT) asm volatile("s_waitcnt vmcnt(6)" ::: "memory");
    else            asm volatile("s_waitcnt vmcnt(0)" ::: "memory");
    blockbar();
    readA(cur);
    readB(cur, 0, br01);
    if (t + 2 < NT) { stage(nx2, 0, t + 2); stage(nx2, 1, t + 2); }
    quad(0, br01);
    // ph2
    blockbar();
    readB(cur, 2, br23);
    if (t + 2 < NT) stage(nx2, 2, t + 2);
    quad(2, br23);
  }

  // epilogue: exp -> bf16 P direct stores + shfl rowsum + atomic
  #pragma unroll
  for (int rf = 0; rf < 4; ++rf) {
    float e[4][4];
    #pragma unroll
    for (int cf = 0; cf < 4; ++cf)
      #pragma unroll
      for (int j = 0; j < 4; ++j)
        e[cf][j] = __expf(acc[rf][cf][j]);
    #pragma unroll
    for (int j = 0; j < 4; ++j) {
      const size_t m = m0 + wm*64 + rf*16 + lhi*4 + j;
      #pragma unroll
      for (int cf = 0; cf < 4; ++cf) {
        const size_t n = n0 + wn*64 + cf*16 + llo;
        Pout[m * (size_t)ldC + n] = f2bf(e[cf][j]);
      }
      float rp = (e[0][j] + e[1][j]) + (e[2][j] + e[3][j]);
      rp += __shfl_xor(rp, 1, 64);
      rp += __shfl_xor(rp, 2, 64);
      rp += __shfl_xor(rp, 4, 64);
      rp += __shfl_xor(rp, 8, 64);
      if (llo == 0) atomicAdd(&rowsum[m], rp);
    }
  }
}

// ================= GEMM2: 256x256 pipelined (C = A * B^T / rowsum) =================
// R16-verbatim (the 355us configuration).
template <int EPI>
__global__ __launch_bounds__(512, 2) void gemm_bt(
    const ushort* __restrict__ A, const ushort* __restrict__ B,
    int aStride, int bStride,      // row strides in BYTES
    int NT,                        // K / 64
    ushort* __restrict__ Pout, float* __restrict__ Oout,
    float* __restrict__ rowsum,
    int ldC)                       // C row stride in ELEMENTS
{
  __shared__ ushort lds[2][4][8192];   // [buf][slot:A0,A1,B0,B1][16KB]
  char* ldsb = (char*)&lds[0][0][0];

  const int tid = threadIdx.x;
  const int w   = tid >> 6;
  const int l   = tid & 63;
  const int lhi = l >> 4;
  const int llo = l & 15;
  const int wm  = w >> 2;        // 0..1
  const int wn  = w & 3;         // 0..3
  const size_t m0 = (size_t)blockIdx.x * 256;
  const size_t n0 = (size_t)blockIdx.y * 256;

  const char* Ab = (const char*)A;
  const char* Bb = (const char*)B;

  const int srow = tid >> 3;           // 0..63
  const int scb  = (tid & 7) * 16;     // 0..112
  auto stage = [&](int buf, int slot, int t) {
    const char* src; int stride; size_t r0;
    if (slot < 2) { src = Ab; stride = aStride; r0 = m0 + (size_t)slot * 128; }
    else          { src = Bb; stride = bStride; r0 = n0 + (size_t)(slot - 2) * 128; }
    char* lbase = ldsb + ((buf*4 + slot) * 16384) + w * 1024;   // wave-uniform
    {
      const int row = srow;
      const char* g = src + (r0 + row) * (size_t)stride + t*128 + (scb ^ ((row & 7) << 4));
      __builtin_amdgcn_global_load_lds(GLP(g), LDP(lbase), 16, 0, 0);
    }
    {
      const int row = srow + 64;
      const char* g = src + (r0 + row) * (size_t)stride + t*128 + (scb ^ ((row & 7) << 4));
      __builtin_amdgcn_global_load_lds(GLP(g), LDP(lbase + 8192), 16, 0, 0);
    }
  };

  const unsigned swz = (unsigned)((l & 7) << 4);
  short8 ar[4][2], br01[2][2], br23[2][2];
  f32x4 acc[8][4] = {};

  const char* aBase0 = ldsb + wm * 16384;
  const char* bBase0 = ldsb + (2 + (wn >> 1)) * 16384;
  const unsigned bRow0 = (unsigned)((wn & 1) * 64);

  auto readA = [&](int buf, int rfB) {
    const char* base = aBase0 + buf * 65536;
    #pragma unroll
    for (int rf = 0; rf < 4; ++rf)
      #pragma unroll
      for (int kk = 0; kk < 2; ++kk) {
        unsigned off = (unsigned)(((rfB + rf) * 16 + llo) * 128)
                     + (((unsigned)(kk*64 + lhi*16)) ^ swz);
        ar[rf][kk] = *(const short8*)(base + off);
      }
  };
  auto readB = [&](int buf, int cfB, short8 (&br)[2][2]) {
    const char* base = bBase0 + buf * 65536;
    #pragma unroll
    for (int c = 0; c < 2; ++c)
      #pragma unroll
      for (int kk = 0; kk < 2; ++kk) {
        unsigned off = (unsigned)((bRow0 + (cfB + c) * 16 + llo) * 128)
                     + (((unsigned)(kk*64 + lhi*16)) ^ swz);
        br[c][kk] = *(const short8*)(base + off);
      }
  };
  auto quad = [&](int rfB, int cfB, short8 (&br)[2][2]) {
    __builtin_amdgcn_s_setprio(1);
    #pragma unroll
    for (int kk = 0; kk < 2; ++kk)
      #pragma unroll
      for (int rf = 0; rf < 4; ++rf)
        #pragma unroll
        for (int c = 0; c < 2; ++c)
          acc[rfB+rf][cfB+c] = __builtin_amdgcn_mfma_f32_16x16x32_bf16(
              ar[rf][kk], br[c][kk], acc[rfB+rf][cfB+c], 0, 0, 0);
    __builtin_amdgcn_s_setprio(0);
  };

  // prologue: B0(0),A0(0),A1(0),B1(0),B0(1),A0(1)
  stage(0, 2, 0); stage(0, 0, 0); stage(0, 1, 0); stage(0, 3, 0);
  stage(1, 2, 1); stage(1, 0, 1);

  for (int t = 0; t < NT; ++t) {
    const int cur = t & 1, nxt = cur ^ 1;
    // ph1
    if (t + 1 < NT) asm volatile("s_waitcnt vmcnt(4)" ::: "memory");
    else            asm volatile("s_waitcnt vmcnt(0)" ::: "memory");
    blockbar();
    readA(cur, 0);
    readB(cur, 0, br01);
    if (t + 1 < NT) stage(nxt, 1, t + 1);
    quad(0, 0, br01);
    // ph2
    blockbar();
    readB(cur, 2, br23);
    if (t + 1 < NT) stage(nxt, 3, t + 1);
    quad(0, 2, br23);
    // ph3
    blockbar();
    readA(cur, 4);
    if (t + 2 < NT) stage(cur, 2, t + 2);
    quad(4, 2, br23);
    // ph4
    blockbar();
    if (t + 2 < NT) stage(cur, 0, t + 2);
    quad(4, 0, br01);
  }

  // ---- epilogue ----
  if (EPI == 0) {
    #pragma unroll
    for (int rf = 0; rf < 8; ++rf) {
      float e[4][4];
      #pragma unroll
      for (int cf = 0; cf < 4; ++cf)
        #pragma unroll
        for (int j = 0; j < 4; ++j)
          e[cf][j] = __expf(acc[rf][cf][j]);
      #pragma unroll
      for (int j = 0; j < 4; ++j) {
        const size_t m = m0 + wm*128 + rf*16 + lhi*4 + j;
        #pragma unroll
        for (int cf = 0; cf < 4; ++cf) {
          const size_t n = n0 + wn*64 + cf*16 + llo;
          Pout[m * (size_t)ldC + n] = f2bf(e[cf][j]);
        }
        float rp = (e[0][j] + e[1][j]) + (e[2][j] + e[3][j]);
        rp += __shfl_xor(rp, 1, 64);
        rp += __shfl_xor(rp, 2, 64);
        rp += __shfl_xor(rp, 4, 64);
        rp += __shfl_xor(rp, 8, 64);
        if (llo == 0) atomicAdd(&rowsum[m], rp);
      }
    }
  } else {
    #pragma unroll
    for (int rf = 0; rf < 8; ++rf)
      #pragma unroll
      for (int j = 0; j < 4; ++j) {
        const size_t m = m0 + wm*128 + rf*16 + lhi*4 + j;
        const float inv = 1.0f / rowsum[m];
        #pragma unroll
        for (int cf = 0; cf < 4; ++cf) {
          const size_t n = n0 + wn*64 + cf*16 + llo;
          Oout[m * (size_t)ldC + n] = acc[rf][cf][j] * inv;
        }
      }
  }
}

// ================= fallback: R7 fused kernel (proven, ~586us) =================
constexpr int BMf = 64, BHf = 256, NHf = S_DIM / BHf, NWf = 8;
constexpr int PBUFf = BMf * BHf * 2;

__global__ __launch_bounds__(512, 2) void attn_fused(
    const float* __restrict__ Q, const ushort* __restrict__ Kn,
    const ushort* __restrict__ Vt, float* __restrict__ out)
{
  __shared__ ushort q_s[BMf * D_DIM];
  __shared__ ushort p_s[2 * BMf * BHf];
  __shared__ float  rs_lds[NWf * BMf];
  __shared__ float  rs_tot[BMf];
  char* qb = (char*)q_s;
  char* pb = (char*)p_s;
  const int tid = threadIdx.x;
  const int w   = tid >> 6;
  const int l   = tid & 63;
  const int lhi = l >> 4;
  const int llo = l & 15;
  const size_t q0 = (size_t)blockIdx.x * BMf;
  {
    const int row = tid >> 3;
    const int c   = tid & 7;
    const unsigned swzr = (unsigned)((row & 7) << 4);
    const float4* src = (const float4*)(Q + (q0 + row) * D_DIM);
    float4 t[16];
    float ss = 0.f;
    #pragma unroll
    for (int i = 0; i < 16; ++i) {
      t[i] = src[c + i*8];
      ss += t[i].x*t[i].x + t[i].y*t[i].y + t[i].z*t[i].z + t[i].w*t[i].w;
    }
    ss += __shfl_xor(ss, 1, 64);
    ss += __shfl_xor(ss, 2, 64);
    ss += __shfl_xor(ss, 4, 64);
    const float sc = 1.0f / fmaxf(sqrtf(ss), 1e-12f);
    #pragma unroll
    for (int i = 0; i < 16; ++i) {
      u32x2 pv;
      pv[0] = (unsigned)f2bf(t[i].x*sc) | ((unsigned)f2bf(t[i].y*sc) << 16);
      pv[1] = (unsigned)f2bf(t[i].z*sc) | ((unsigned)f2bf(t[i].w*sc) << 16);
      unsigned byte = (unsigned)(row*1024) + (((unsigned)(c*8 + i*64)) ^ swzr);
      *(u32x2*)(qb + byte) = pv;
    }
  }
  __syncthreads();
  f32x4 o[4][4] = {};
  float rs_acc[4] = {0.f, 0.f, 0.f, 0.f};
  const unsigned swz = (unsigned)((l & 7) << 4);
  unsigned rowbQ[4], rowbP[4];
  #pragma unroll
  for (int qf = 0; qf < 4; ++qf) {
    rowbQ[qf] = (unsigned)((qf*16 + llo) * 1024);
    rowbP[qf] = (unsigned)((qf*16 + llo) * 512);
  }
  auto do_qkt = [&](int h, f32x4 (&sacc)[2][4]) {
    const short8* kp[2];
    #pragma unroll
    for (int kf = 0; kf < 2; ++kf)
      kp[kf] = (const short8*)(Kn + (size_t)(h*BHf + w*32 + kf*16 + llo) * D_DIM + lhi*8);
    __builtin_amdgcn_s_setprio(1);
    #pragma unroll
    for (int ks = 0; ks < 16; ++ks) {
      const unsigned off = ((unsigned)(ks*64 + lhi*16)) ^ swz;
      short8 a[2], b[4];
      #pragma unroll
      for (int kf = 0; kf < 2; ++kf) a[kf] = kp[kf][ks*4];
      #pragma unroll
      for (int qf = 0; qf < 4; ++qf)
        b[qf] = *(const short8*)(qb + (rowbQ[qf] + off));
      #pragma unroll
      for (int kf = 0; kf < 2; ++kf)
        #pragma unroll
        for (int qf = 0; qf < 4; ++qf)
          sacc[kf][qf] = __builtin_amdgcn_mfma_f32_16x16x32_bf16(a[kf], b[qf], sacc[kf][qf], 0, 0, 0);
    }
    __builtin_amdgcn_s_setprio(0);
  };
  auto do_exp = [&](f32x4 (&sacc)[2][4], u32x2 (&pk)[2][4]) {
    #pragma unroll
    for (int kf = 0; kf < 2; ++kf)
      #pragma unroll
      for (int qf = 0; qf < 4; ++qf) {
        float p0 = __expf(sacc[kf][qf][0]);
        float p1 = __expf(sacc[kf][qf][1]);
        float p2 = __expf(sacc[kf][qf][2]);
        float p3 = __expf(sacc[kf][qf][3]);
        rs_acc[qf] += (p0 + p1) + (p2 + p3);
        pk[kf][qf][0] = (unsigned)f2bf(p0) | ((unsigned)f2bf(p1) << 16);
        pk[kf][qf][1] = (unsigned)f2bf(p2) | ((unsigned)f2bf(p3) << 16);
      }
  };
  auto do_pwrite = [&](u32x2 (&pk)[2][4], char* buf) {
    #pragma unroll
    for (int kf = 0; kf < 2; ++kf)
      #pragma unroll
      for (int qf = 0; qf < 4; ++qf) {
        unsigned lin = (unsigned)(w*64 + kf*32 + lhi*8);
        *(u32x2*)(buf + rowbP[qf] + (lin ^ swz)) = pk[kf][qf];
      }
  };
  auto do_pv = [&](int h, const char* buf) {
    const short8* vp[4];
    #pragma unroll
    for (int df = 0; df < 4; ++df)
      vp[df] = (const short8*)(Vt + (size_t)(w*64 + df*16 + llo) * S_DIM + h*BHf + lhi*8);
    __builtin_amdgcn_s_setprio(1);
    #pragma unroll
    for (int ks = 0; ks < 8; ++ks) {
      const unsigned off = ((unsigned)(ks*64 + lhi*16)) ^ swz;
      short8 a[4], b[4];
      #pragma unroll
      for (int qf = 0; qf < 4; ++qf)
        a[qf] = *(const short8*)(buf + (rowbP[qf] + off));
      #pragma unroll
      for (int df = 0; df < 4; ++df) b[df] = vp[df][ks*4];
      #pragma unroll
      for (int qf = 0; qf < 4; ++qf)
        #pragma unroll
        for (int df = 0; df < 4; ++df)
          o[qf][df] = __builtin_amdgcn_mfma_f32_16x16x32_bf16(a[qf], b[df], o[qf][df], 0, 0, 0);
    }
    __builtin_amdgcn_s_setprio(0);
  };
  {
    f32x4 sacc[2][4] = {};
    do_qkt(0, sacc);
    u32x2 pk[2][4];
    do_exp(sacc, pk);
    do_pwrite(pk, pb + 0);
  }
  __syncthreads();
  for (int i = 0; i < NHf - 1; ++i) {
    f32x4 sacc[2][4] = {};
    do_qkt(i + 1, sacc);
    u32x2 pk[2][4];
    do_exp(sacc, pk);
    do_pv(i, pb + (i & 1) * PBUFf);
    do_pwrite(pk, pb + ((i + 1) & 1) * PBUFf);
    __syncthreads();
  }
  do_pv(NHf - 1, pb + ((NHf - 1) & 1) * PBUFf);
  #pragma unroll
  for (int qf = 0; qf < 4; ++qf) {
    float v = rs_acc[qf];
    v += __shfl_xor(v, 16, 64);
    v += __shfl_xor(v, 32, 64);
    if (l < 16) rs_lds[w*BMf + qf*16 + llo] = v;
  }
  __syncthreads();
  if (tid < BMf) {
    float tot = 0.f;
    #pragma unroll
    for (int ww = 0; ww < NWf; ++ww) tot += rs_lds[ww*BMf + tid];
    rs_tot[tid] = tot;
  }
  __syncthreads();
  #pragma unroll
  for (int qf = 0; qf < 4; ++qf)
    #pragma unroll
    for (int r = 0; r < 4; ++r) {
      const int query = qf*16 + lhi*4 + r;
      const float inv = 1.0f / rs_tot[query];
      #pragma unroll
      for (int df = 0; df < 4; ++df) {
        const int dim = w*64 + df*16 + llo;
        out[(q0 + query) * D_DIM + dim] = o[qf][df][r] * inv;
      }
    }
}

extern "C" void kernel_launch(void* const* d_in, const int* in_sizes, int n_in,
                              void* d_out, int out_size, void* d_ws, size_t ws_size,
                              hipStream_t stream) {
  const float* Q = (const float*)d_in[0];
  const float* K = (const float*)d_in[1];
  const float* V = (const float*)d_in[2];
  float* out = (float*)d_out;
  const int N = in_sizes[0] / D_DIM;          // 65536

  ushort* Kn = (ushort*)d_ws;                                // [S][D] bf16, 2MB
  ushort* Vt = Kn + (size_t)S_DIM * D_DIM;                   // [D][S] bf16, 2MB
  char*   rest = (char*)(Vt + (size_t)D_DIM * S_DIM);
  const size_t base_bytes = (size_t)S_DIM * D_DIM * 2 * 2;   // 4MB
  const size_t avail = ws_size > base_bytes ? ws_size - base_bytes : 0;

  // bytes per chunk-row: Qn (D*2) + P (S*2) + rowsum (4). Cap chunk at 32768
  // so P (<=128MB) stays L3-resident for GEMM2 (65536 would spill: R13/R14).
  const size_t perRow = (size_t)D_DIM*2 + (size_t)S_DIM*2 + 4;
  int chunk = 0;
  const int cand[4] = {32768, 16384, 8192, 4096};
  for (int i = 0; i < 4; ++i)
    if ((size_t)cand[i] * perRow <= avail && (N % cand[i]) == 0) { chunk = cand[i]; break; }

  k_norm<<<S_DIM/4, 256, 0, stream>>>(K, Kn, nullptr);
  k_transpose_v<<<dim3(S_DIM/64, D_DIM/64), 256, 0, stream>>>(V, Vt);

  if (chunk == 0) {
    attn_fused<<<N/BMf, 512, 0, stream>>>(Q, Kn, Vt, out);
    return;
  }

  ushort* Qn = (ushort*)rest;                                 // [chunk][D]
  ushort* P  = Qn + (size_t)chunk * D_DIM;                    // [chunk][S]
  float* rowsum = (float*)(P + (size_t)chunk * S_DIM);        // [chunk]

  for (int c = 0; c < N; c += chunk) {
    // Q-norm also zero-inits rowsum (replaces hipMemsetAsync)
    k_norm<<<chunk/4, 256, 0, stream>>>(Q + (size_t)c * D_DIM, Qn, rowsum);
    // GEMM1: P = exp(Qn * Kn^T), rowsum += row sums -- 128x256 2-phase 3-buf
    gemm1_bt<<<dim3(chunk/128, S_DIM/256), 512, 0, stream>>>(
        Qn, Kn, D_DIM*2, D_DIM*2, D_DIM/64, P, rowsum, S_DIM);
    // GEMM2: out = (P * Vt^T) / rowsum -- R16 256x256 form
    gemm_bt<1><<<dim3(chunk/256, D_DIM/256), 512, 0, stream>>>(
        P, Vt, S_DIM*2, S_DIM*2, S_DIM/64, nullptr,
        out + (size_t)c * D_DIM, rowsum, D_DIM);
  }
}

// Round 18
// 352.858 us; speedup vs baseline: 1.0928x; 1.0928x over previous
//
#include <hip/hip_runtime.h>
#include <hip/hip_bf16.h>

typedef __attribute__((ext_vector_type(8))) short short8;   // 8 bf16 (4 VGPR)
typedef __attribute__((ext_vector_type(4))) float f32x4;
typedef __attribute__((ext_vector_type(2))) unsigned int u32x2;

constexpr int D_DIM = 512;
constexpr int S_DIM = 2048;

static __device__ __forceinline__ unsigned short f2bf(float f) {
  __hip_bfloat16 h = __float2bfloat16(f);
  return *reinterpret_cast<unsigned short*>(&h);
}

#define GLP(p) ((const __attribute__((address_space(1))) unsigned int*)(p))
#define LDP(p) ((__attribute__((address_space(3))) unsigned int*)(p))

static __device__ __forceinline__ void blockbar() {
  asm volatile("" ::: "memory");
  __builtin_amdgcn_s_barrier();
  asm volatile("" ::: "memory");
}

// ---- setup: L2-normalize rows -> bf16 [rows][512], one wave per row ----
__global__ void k_norm(const float* __restrict__ K, ushort* __restrict__ Kn) {
  const int row = blockIdx.x * 4 + (threadIdx.x >> 6);
  const int l   = threadIdx.x & 63;
  const float* src = K + (size_t)row * D_DIM + l * 8;
  float4 v0 = *(const float4*)(src);
  float4 v1 = *(const float4*)(src + 4);
  float ss = v0.x*v0.x + v0.y*v0.y + v0.z*v0.z + v0.w*v0.w
           + v1.x*v1.x + v1.y*v1.y + v1.z*v1.z + v1.w*v1.w;
  #pragma unroll
  for (int off = 1; off < 64; off <<= 1) ss += __shfl_xor(ss, off, 64);
  const float sc = 1.0f / fmaxf(sqrtf(ss), 1e-12f);
  float f[8] = {v0.x,v0.y,v0.z,v0.w,v1.x,v1.y,v1.z,v1.w};
  unsigned uu[4];
  #pragma unroll
  for (int i = 0; i < 4; ++i)
    uu[i] = (unsigned)f2bf(f[2*i]*sc) | ((unsigned)f2bf(f[2*i+1]*sc) << 16);
  *(uint4*)(Kn + (size_t)row * D_DIM + l*8) = make_uint4(uu[0],uu[1],uu[2],uu[3]);
}

// ---- setup: transpose V[S][D] f32 -> Vt[D][S] bf16 ----
__global__ void k_transpose_v(const float* __restrict__ V, ushort* __restrict__ Vt) {
  __shared__ float tile[64][65];
  const int s0 = blockIdx.x * 64;
  const int d0 = blockIdx.y * 64;
  const int tj = threadIdx.x & 63;
  const int ti = threadIdx.x >> 6;
  #pragma unroll
  for (int k = 0; k < 16; ++k) {
    int s = ti + 4*k;
    tile[s][tj] = V[(size_t)(s0+s) * D_DIM + d0 + tj];
  }
  __syncthreads();
  #pragma unroll
  for (int k = 0; k < 16; ++k) {
    int d = ti + 4*k;
    Vt[(size_t)(d0+d) * S_DIM + s0 + tj] = f2bf(tile[tj][d]);
  }
}

// ================= 256x256 pipelined GEMM (C = A * B^T), bf16 in =================
// R16-verbatim main loop. EPI 0 (GEMM1): C=exp(acc) -> bf16 Pout; NO rowsum
// (no atomics, no shfl -- rowsum moved to GEMM2). EPI 1 (GEMM2): additionally
// accumulates acc_rs[rf] = sum_k A[m][k] via a ones-operand MFMA per (rf,kk)
// (every output column equals the row sum -> divisor is LANE-LOCAL), then
// Oout = acc / acc_rs.
template <int EPI>
__global__ __launch_bounds__(512, 2) void gemm_bt(
    const ushort* __restrict__ A, const ushort* __restrict__ B,
    int aStride, int bStride,      // row strides in BYTES
    int NT,                        // K / 64
    ushort* __restrict__ Pout, float* __restrict__ Oout,
    int ldC)                       // C row stride in ELEMENTS
{
  __shared__ ushort lds[2][4][8192];   // [buf][slot:A0,A1,B0,B1][16KB]
  char* ldsb = (char*)&lds[0][0][0];

  const int tid = threadIdx.x;
  const int w   = tid >> 6;
  const int l   = tid & 63;
  const int lhi = l >> 4;
  const int llo = l & 15;
  const int wm  = w >> 2;        // 0..1
  const int wn  = w & 3;         // 0..3
  const size_t m0 = (size_t)blockIdx.x * 256;
  const size_t n0 = (size_t)blockIdx.y * 256;

  const char* Ab = (const char*)A;
  const char* Bb = (const char*)B;

  // staging: thread covers slot bytes tid*16 and 8192 + tid*16
  const int srow = tid >> 3;           // 0..63
  const int scb  = (tid & 7) * 16;     // 0..112
  auto stage = [&](int buf, int slot, int t) {
    const char* src; int stride; size_t r0;
    if (slot < 2) { src = Ab; stride = aStride; r0 = m0 + (size_t)slot * 128; }
    else          { src = Bb; stride = bStride; r0 = n0 + (size_t)(slot - 2) * 128; }
    char* lbase = ldsb + ((buf*4 + slot) * 16384) + w * 1024;   // wave-uniform
    {
      const int row = srow;
      const char* g = src + (r0 + row) * (size_t)stride + t*128 + (scb ^ ((row & 7) << 4));
      __builtin_amdgcn_global_load_lds(GLP(g), LDP(lbase), 16, 0, 0);
    }
    {
      const int row = srow + 64;
      const char* g = src + (r0 + row) * (size_t)stride + t*128 + (scb ^ ((row & 7) << 4));
      __builtin_amdgcn_global_load_lds(GLP(g), LDP(lbase + 8192), 16, 0, 0);
    }
  };

  const unsigned swz = (unsigned)((l & 7) << 4);
  short8 ar[4][2], br01[2][2], br23[2][2];
  f32x4 acc[8][4] = {};
  f32x4 acc_rs[8] = {};                // GEMM2 rowsum accumulator (EPI==1)
  short8 ones;
  #pragma unroll
  for (int i = 0; i < 8; ++i) ones[i] = (short)0x3F80;   // bf16 1.0

  const char* aBase0 = ldsb + wm * 16384;
  const char* bBase0 = ldsb + (2 + (wn >> 1)) * 16384;
  const unsigned bRow0 = (unsigned)((wn & 1) * 64);

  auto readA = [&](int buf, int rfB) {
    const char* base = aBase0 + buf * 65536;
    #pragma unroll
    for (int rf = 0; rf < 4; ++rf)
      #pragma unroll
      for (int kk = 0; kk < 2; ++kk) {
        unsigned off = (unsigned)(((rfB + rf) * 16 + llo) * 128)
                     + (((unsigned)(kk*64 + lhi*16)) ^ swz);
        ar[rf][kk] = *(const short8*)(base + off);
      }
  };
  auto readB = [&](int buf, int cfB, short8 (&br)[2][2]) {
    const char* base = bBase0 + buf * 65536;
    #pragma unroll
    for (int c = 0; c < 2; ++c)
      #pragma unroll
      for (int kk = 0; kk < 2; ++kk) {
        unsigned off = (unsigned)((bRow0 + (cfB + c) * 16 + llo) * 128)
                     + (((unsigned)(kk*64 + lhi*16)) ^ swz);
        br[c][kk] = *(const short8*)(base + off);
      }
  };
  auto quad = [&](int rfB, int cfB, short8 (&br)[2][2]) {
    __builtin_amdgcn_s_setprio(1);
    #pragma unroll
    for (int kk = 0; kk < 2; ++kk) {
      #pragma unroll
      for (int rf = 0; rf < 4; ++rf) {
        #pragma unroll
        for (int c = 0; c < 2; ++c)
          acc[rfB+rf][cfB+c] = __builtin_amdgcn_mfma_f32_16x16x32_bf16(
              ar[rf][kk], br[c][kk], acc[rfB+rf][cfB+c], 0, 0, 0);
        if (EPI == 1 && cfB == 0)     // rowsum: once per (rf,kk) per tile
          acc_rs[rfB+rf] = __builtin_amdgcn_mfma_f32_16x16x32_bf16(
              ar[rf][kk], ones, acc_rs[rfB+rf], 0, 0, 0);
      }
    }
    __builtin_amdgcn_s_setprio(0);
  };

  // prologue: B0(0),A0(0),A1(0),B1(0),B0(1),A0(1)
  stage(0, 2, 0); stage(0, 0, 0); stage(0, 1, 0); stage(0, 3, 0);
  stage(1, 2, 1); stage(1, 0, 1);

  for (int t = 0; t < NT; ++t) {
    const int cur = t & 1, nxt = cur ^ 1;
    // ph1
    if (t + 1 < NT) asm volatile("s_waitcnt vmcnt(4)" ::: "memory");
    else            asm volatile("s_waitcnt vmcnt(0)" ::: "memory");
    blockbar();
    readA(cur, 0);
    readB(cur, 0, br01);
    if (t + 1 < NT) stage(nxt, 1, t + 1);
    quad(0, 0, br01);
    // ph2
    blockbar();
    readB(cur, 2, br23);
    if (t + 1 < NT) stage(nxt, 3, t + 1);
    quad(0, 2, br23);
    // ph3
    blockbar();
    readA(cur, 4);
    if (t + 2 < NT) stage(cur, 2, t + 2);
    quad(4, 2, br23);
    // ph4
    blockbar();
    if (t + 2 < NT) stage(cur, 0, t + 2);
    quad(4, 0, br01);
  }

  // ---- epilogue ----
  if (EPI == 0) {
    // exp -> bf16 P stores only (rowsum computed in GEMM2)
    #pragma unroll
    for (int rf = 0; rf < 8; ++rf) {
      float e[4][4];
      #pragma unroll
      for (int cf = 0; cf < 4; ++cf)
        #pragma unroll
        for (int j = 0; j < 4; ++j)
          e[cf][j] = __expf(acc[rf][cf][j]);
      #pragma unroll
      for (int j = 0; j < 4; ++j) {
        const size_t m = m0 + wm*128 + rf*16 + lhi*4 + j;
        #pragma unroll
        for (int cf = 0; cf < 4; ++cf) {
          const size_t n = n0 + wn*64 + cf*16 + llo;
          Pout[m * (size_t)ldC + n] = f2bf(e[cf][j]);
        }
      }
    }
  } else {
    // divide by lane-local rowsum, store f32
    #pragma unroll
    for (int rf = 0; rf < 8; ++rf)
      #pragma unroll
      for (int j = 0; j < 4; ++j) {
        const size_t m = m0 + wm*128 + rf*16 + lhi*4 + j;
        const float inv = 1.0f / acc_rs[rf][j];
        #pragma unroll
        for (int cf = 0; cf < 4; ++cf) {
          const size_t n = n0 + wn*64 + cf*16 + llo;
          Oout[m * (size_t)ldC + n] = acc[rf][cf][j] * inv;
        }
      }
  }
}

// ================= fallback: R7 fused kernel (proven, ~586us) =================
constexpr int BMf = 64, BHf = 256, NHf = S_DIM / BHf, NWf = 8;
constexpr int PBUFf = BMf * BHf * 2;

__global__ __launch_bounds__(512, 2) void attn_fused(
    const float* __restrict__ Q, const ushort* __restrict__ Kn,
    const ushort* __restrict__ Vt, float* __restrict__ out)
{
  __shared__ ushort q_s[BMf * D_DIM];
  __shared__ ushort p_s[2 * BMf * BHf];
  __shared__ float  rs_lds[NWf * BMf];
  __shared__ float  rs_tot[BMf];
  char* qb = (char*)q_s;
  char* pb = (char*)p_s;
  const int tid = threadIdx.x;
  const int w   = tid >> 6;
  const int l   = tid & 63;
  const int lhi = l >> 4;
  const int llo = l & 15;
  const size_t q0 = (size_t)blockIdx.x * BMf;
  {
    const int row = tid >> 3;
    const int c   = tid & 7;
    const unsigned swzr = (unsigned)((row & 7) << 4);
    const float4* src = (const float4*)(Q + (q0 + row) * D_DIM);
    float4 t[16];
    float ss = 0.f;
    #pragma unroll
    for (int i = 0; i < 16; ++i) {
      t[i] = src[c + i*8];
      ss += t[i].x*t[i].x + t[i].y*t[i].y + t[i].z*t[i].z + t[i].w*t[i].w;
    }
    ss += __shfl_xor(ss, 1, 64);
    ss += __shfl_xor(ss, 2, 64);
    ss += __shfl_xor(ss, 4, 64);
    const float sc = 1.0f / fmaxf(sqrtf(ss), 1e-12f);
    #pragma unroll
    for (int i = 0; i < 16; ++i) {
      u32x2 pv;
      pv[0] = (unsigned)f2bf(t[i].x*sc) | ((unsigned)f2bf(t[i].y*sc) << 16);
      pv[1] = (unsigned)f2bf(t[i].z*sc) | ((unsigned)f2bf(t[i].w*sc) << 16);
      unsigned byte = (unsigned)(row*1024) + (((unsigned)(c*8 + i*64)) ^ swzr);
      *(u32x2*)(qb + byte) = pv;
    }
  }
  __syncthreads();
  f32x4 o[4][4] = {};
  float rs_acc[4] = {0.f, 0.f, 0.f, 0.f};
  const unsigned swz = (unsigned)((l & 7) << 4);
  unsigned rowbQ[4], rowbP[4];
  #pragma unroll
  for (int qf = 0; qf < 4; ++qf) {
    rowbQ[qf] = (unsigned)((qf*16 + llo) * 1024);
    rowbP[qf] = (unsigned)((qf*16 + llo) * 512);
  }
  auto do_qkt = [&](int h, f32x4 (&sacc)[2][4]) {
    const short8* kp[2];
    #pragma unroll
    for (int kf = 0; kf < 2; ++kf)
      kp[kf] = (const short8*)(Kn + (size_t)(h*BHf + w*32 + kf*16 + llo) * D_DIM + lhi*8);
    __builtin_amdgcn_s_setprio(1);
    #pragma unroll
    for (int ks = 0; ks < 16; ++ks) {
      const unsigned off = ((unsigned)(ks*64 + lhi*16)) ^ swz;
      short8 a[2], b[4];
      #pragma unroll
      for (int kf = 0; kf < 2; ++kf) a[kf] = kp[kf][ks*4];
      #pragma unroll
      for (int qf = 0; qf < 4; ++qf)
        b[qf] = *(const short8*)(qb + (rowbQ[qf] + off));
      #pragma unroll
      for (int kf = 0; kf < 2; ++kf)
        #pragma unroll
        for (int qf = 0; qf < 4; ++qf)
          sacc[kf][qf] = __builtin_amdgcn_mfma_f32_16x16x32_bf16(a[kf], b[qf], sacc[kf][qf], 0, 0, 0);
    }
    __builtin_amdgcn_s_setprio(0);
  };
  auto do_exp = [&](f32x4 (&sacc)[2][4], u32x2 (&pk)[2][4]) {
    #pragma unroll
    for (int kf = 0; kf < 2; ++kf)
      #pragma unroll
      for (int qf = 0; qf < 4; ++qf) {
        float p0 = __expf(sacc[kf][qf][0]);
        float p1 = __expf(sacc[kf][qf][1]);
        float p2 = __expf(sacc[kf][qf][2]);
        float p3 = __expf(sacc[kf][qf][3]);
        rs_acc[qf] += (p0 + p1) + (p2 + p3);
        pk[kf][qf][0] = (unsigned)f2bf(p0) | ((unsigned)f2bf(p1) << 16);
        pk[kf][qf][1] = (unsigned)f2bf(p2) | ((unsigned)f2bf(p3) << 16);
      }
  };
  auto do_pwrite = [&](u32x2 (&pk)[2][4], char* buf) {
    #pragma unroll
    for (int kf = 0; kf < 2; ++kf)
      #pragma unroll
      for (int qf = 0; qf < 4; ++qf) {
        unsigned lin = (unsigned)(w*64 + kf*32 + lhi*8);
        *(u32x2*)(buf + rowbP[qf] + (lin ^ swz)) = pk[kf][qf];
      }
  };
  auto do_pv = [&](int h, const char* buf) {
    const short8* vp[4];
    #pragma unroll
    for (int df = 0; df < 4; ++df)
      vp[df] = (const short8*)(Vt + (size_t)(w*64 + df*16 + llo) * S_DIM + h*BHf + lhi*8);
    __builtin_amdgcn_s_setprio(1);
    #pragma unroll
    for (int ks = 0; ks < 8; ++ks) {
      const unsigned off = ((unsigned)(ks*64 + lhi*16)) ^ swz;
      short8 a[4], b[4];
      #pragma unroll
      for (int qf = 0; qf < 4; ++qf)
        a[qf] = *(const short8*)(buf + (rowbP[qf] + off));
      #pragma unroll
      for (int df = 0; df < 4; ++df) b[df] = vp[df][ks*4];
      #pragma unroll
      for (int qf = 0; qf < 4; ++qf)
        #pragma unroll
        for (int df = 0; df < 4; ++df)
          o[qf][df] = __builtin_amdgcn_mfma_f32_16x16x32_bf16(a[qf], b[df], o[qf][df], 0, 0, 0);
    }
    __builtin_amdgcn_s_setprio(0);
  };
  {
    f32x4 sacc[2][4] = {};
    do_qkt(0, sacc);
    u32x2 pk[2][4];
    do_exp(sacc, pk);
    do_pwrite(pk, pb + 0);
  }
  __syncthreads();
  for (int i = 0; i < NHf - 1; ++i) {
    f32x4 sacc[2][4] = {};
    do_qkt(i + 1, sacc);
    u32x2 pk[2][4];
    do_exp(sacc, pk);
    do_pv(i, pb + (i & 1) * PBUFf);
    do_pwrite(pk, pb + ((i + 1) & 1) * PBUFf);
    __syncthreads();
  }
  do_pv(NHf - 1, pb + ((NHf - 1) & 1) * PBUFf);
  #pragma unroll
  for (int qf = 0; qf < 4; ++qf) {
    float v = rs_acc[qf];
    v += __shfl_xor(v, 16, 64);
    v += __shfl_xor(v, 32, 64);
    if (l < 16) rs_lds[w*BMf + qf*16 + llo] = v;
  }
  __syncthreads();
  if (tid < BMf) {
    float tot = 0.f;
    #pragma unroll
    for (int ww = 0; ww < NWf; ++ww) tot += rs_lds[ww*BMf + tid];
    rs_tot[tid] = tot;
  }
  __syncthreads();
  #pragma unroll
  for (int qf = 0; qf < 4; ++qf)
    #pragma unroll
    for (int r = 0; r < 4; ++r) {
      const int query = qf*16 + lhi*4 + r;
      const float inv = 1.0f / rs_tot[query];
      #pragma unroll
      for (int df = 0; df < 4; ++df) {
        const int dim = w*64 + df*16 + llo;
        out[(q0 + query) * D_DIM + dim] = o[qf][df][r] * inv;
      }
    }
}

extern "C" void kernel_launch(void* const* d_in, const int* in_sizes, int n_in,
                              void* d_out, int out_size, void* d_ws, size_t ws_size,
                              hipStream_t stream) {
  const float* Q = (const float*)d_in[0];
  const float* K = (const float*)d_in[1];
  const float* V = (const float*)d_in[2];
  float* out = (float*)d_out;
  const int N = in_sizes[0] / D_DIM;          // 65536

  ushort* Kn = (ushort*)d_ws;                                // [S][D] bf16, 2MB
  ushort* Vt = Kn + (size_t)S_DIM * D_DIM;                   // [D][S] bf16, 2MB
  char*   rest = (char*)(Vt + (size_t)D_DIM * S_DIM);
  const size_t base_bytes = (size_t)S_DIM * D_DIM * 2 * 2;   // 4MB
  const size_t avail = ws_size > base_bytes ? ws_size - base_bytes : 0;

  // bytes per chunk-row: Qn (D*2) + P (S*2). Cap chunk at 32768 so P (<=128MB)
  // stays L3-resident for GEMM2 (65536 spills: R13/R14 evidence).
  const size_t perRow = (size_t)D_DIM*2 + (size_t)S_DIM*2;
  int chunk = 0;
  const int cand[4] = {32768, 16384, 8192, 4096};
  for (int i = 0; i < 4; ++i)
    if ((size_t)cand[i] * perRow <= avail && (N % cand[i]) == 0) { chunk = cand[i]; break; }

  k_norm<<<S_DIM/4, 256, 0, stream>>>(K, Kn);
  k_transpose_v<<<dim3(S_DIM/64, D_DIM/64), 256, 0, stream>>>(V, Vt);

  if (chunk == 0) {
    attn_fused<<<N/BMf, 512, 0, stream>>>(Q, Kn, Vt, out);
    return;
  }

  ushort* Qn = (ushort*)rest;                                 // [chunk][D]
  ushort* P  = Qn + (size_t)chunk * D_DIM;                    // [chunk][S]

  for (int c = 0; c < N; c += chunk) {
    k_norm<<<chunk/4, 256, 0, stream>>>(Q + (size_t)c * D_DIM, Qn);
    // GEMM1: P = exp(Qn * Kn^T)  (no rowsum, no atomics)
    gemm_bt<0><<<dim3(chunk/256, S_DIM/256), 512, 0, stream>>>(
        Qn, Kn, D_DIM*2, D_DIM*2, D_DIM/64, P, nullptr, S_DIM);
    // GEMM2: out = (P * Vt^T) / rowsum, rowsum from lane-local ones-MFMA
    gemm_bt<1><<<dim3(chunk/256, D_DIM/256), 512, 0, stream>>>(
        P, Vt, S_DIM*2, S_DIM*2, S_DIM/64, nullptr,
        out + (size_t)c * D_DIM, D_DIM);
  }
}

// Round 19
// 345.536 us; speedup vs baseline: 1.1159x; 1.0212x over previous
//
#include <hip/hip_runtime.h>
#include <hip/hip_bf16.h>

typedef __attribute__((ext_vector_type(8))) short short8;   // 8 bf16 (4 VGPR)
typedef __attribute__((ext_vector_type(4))) float f32x4;
typedef __attribute__((ext_vector_type(2))) unsigned int u32x2;

constexpr int D_DIM = 512;
constexpr int S_DIM = 2048;

static __device__ __forceinline__ unsigned short f2bf(float f) {
  __hip_bfloat16 h = __float2bfloat16(f);
  return *reinterpret_cast<unsigned short*>(&h);
}

#define GLP(p) ((const __attribute__((address_space(1))) unsigned int*)(p))
#define LDP(p) ((__attribute__((address_space(3))) unsigned int*)(p))

static __device__ __forceinline__ void blockbar() {
  asm volatile("" ::: "memory");
  __builtin_amdgcn_s_barrier();
  asm volatile("" ::: "memory");
}

// ---- setup: L2-normalize rows -> bf16 [rows][512], one wave per row ----
__global__ void k_norm(const float* __restrict__ K, ushort* __restrict__ Kn) {
  const int row = blockIdx.x * 4 + (threadIdx.x >> 6);
  const int l   = threadIdx.x & 63;
  const float* src = K + (size_t)row * D_DIM + l * 8;
  float4 v0 = *(const float4*)(src);
  float4 v1 = *(const float4*)(src + 4);
  float ss = v0.x*v0.x + v0.y*v0.y + v0.z*v0.z + v0.w*v0.w
           + v1.x*v1.x + v1.y*v1.y + v1.z*v1.z + v1.w*v1.w;
  #pragma unroll
  for (int off = 1; off < 64; off <<= 1) ss += __shfl_xor(ss, off, 64);
  const float sc = 1.0f / fmaxf(sqrtf(ss), 1e-12f);
  float f[8] = {v0.x,v0.y,v0.z,v0.w,v1.x,v1.y,v1.z,v1.w};
  unsigned uu[4];
  #pragma unroll
  for (int i = 0; i < 4; ++i)
    uu[i] = (unsigned)f2bf(f[2*i]*sc) | ((unsigned)f2bf(f[2*i+1]*sc) << 16);
  *(uint4*)(Kn + (size_t)row * D_DIM + l*8) = make_uint4(uu[0],uu[1],uu[2],uu[3]);
}

// ---- setup: transpose V[S][D] f32 -> Vt[D][S] bf16 ----
__global__ void k_transpose_v(const float* __restrict__ V, ushort* __restrict__ Vt) {
  __shared__ float tile[64][65];
  const int s0 = blockIdx.x * 64;
  const int d0 = blockIdx.y * 64;
  const int tj = threadIdx.x & 63;
  const int ti = threadIdx.x >> 6;
  #pragma unroll
  for (int k = 0; k < 16; ++k) {
    int s = ti + 4*k;
    tile[s][tj] = V[(size_t)(s0+s) * D_DIM + d0 + tj];
  }
  __syncthreads();
  #pragma unroll
  for (int k = 0; k < 16; ++k) {
    int d = ti + 4*k;
    Vt[(size_t)(d0+d) * S_DIM + s0 + tj] = f2bf(tile[tj][d]);
  }
}

// ===== GEMM1: 128x256, SINGLE-buffer, 48KB LDS -> 2 blocks/CU =====
// C = exp(A*B^T) -> bf16 Pout (no rowsum; rowsum in GEMM2 via ones-MFMA).
// Schedule: stage(t) -> vmcnt(0) -> bar -> compute(t) -> bar -> stage(t+1).
// The co-resident block's MFMA covers this block's stage-wait (cross-block
// pipelining instead of double-buffering). acc 64 VGPR + per-kk operand reads
// keep total regs <=128 so 2 blocks x 8 waves = 4 waves/SIMD fit.
__global__ __launch_bounds__(512, 4) void gemm1_sb(
    const ushort* __restrict__ A, const ushort* __restrict__ B,
    int aStride, int bStride,      // row strides in BYTES
    int NT,                        // K / 64
    ushort* __restrict__ Pout, int ldC)
{
  __shared__ ushort lds[3][8192];   // [slot:A,B0,B1][16KB] = 48KB
  char* ldsb = (char*)&lds[0][0];

  const int tid = threadIdx.x;
  const int w   = tid >> 6;
  const int l   = tid & 63;
  const int lhi = l >> 4;
  const int llo = l & 15;
  const int wm  = w >> 2;        // 0..1
  const int wn  = w & 3;         // 0..3
  const size_t m0 = (size_t)blockIdx.x * 128;
  const size_t n0 = (size_t)blockIdx.y * 256;

  const int srow = tid >> 3;           // 0..63
  const int scb  = (tid & 7) * 16;     // 0..112
  const unsigned sw = (unsigned)(scb ^ ((srow & 7) << 4));
  const char* gp[3][2];
  #pragma unroll
  for (int slot = 0; slot < 3; ++slot) {
    const char* src; int stride; size_t r0;
    if (slot == 0) { src = (const char*)A; stride = aStride; r0 = m0; }
    else           { src = (const char*)B; stride = bStride; r0 = n0 + (size_t)(slot - 1) * 128; }
    gp[slot][0] = src + (r0 + srow) * (size_t)stride + sw;
    gp[slot][1] = src + (r0 + srow + 64) * (size_t)stride + sw;
  }
  auto stage = [&](int slot, int t) {
    char* lbase = ldsb + slot * 16384 + w * 1024;   // wave-uniform
    const int toff = t * 128;
    __builtin_amdgcn_global_load_lds(GLP(gp[slot][0] + toff), LDP(lbase), 16, 0, 0);
    __builtin_amdgcn_global_load_lds(GLP(gp[slot][1] + toff), LDP(lbase + 8192), 16, 0, 0);
  };

  const unsigned swz = (unsigned)((l & 7) << 4);
  f32x4 acc[4][4] = {};

  const unsigned aRow0 = (unsigned)(wm * 64);
  const int bSlot = 1 + (wn >> 1);
  const unsigned bRow0 = (unsigned)((wn & 1) * 64);
  const char* aBase = ldsb;
  const char* bBase = ldsb + bSlot * 16384;

  // prologue: tile 0
  stage(0, 0); stage(1, 0); stage(2, 0);

  for (int t = 0; t < NT; ++t) {
    asm volatile("s_waitcnt vmcnt(0)" ::: "memory");
    blockbar();
    #pragma unroll
    for (int kk = 0; kk < 2; ++kk) {
      short8 ar[4], br[4];
      const unsigned koff = ((unsigned)(kk*64 + lhi*16)) ^ swz;
      #pragma unroll
      for (int rf = 0; rf < 4; ++rf)
        ar[rf] = *(const short8*)(aBase + (aRow0 + rf*16 + llo) * 128 + koff);
      #pragma unroll
      for (int cf = 0; cf < 4; ++cf)
        br[cf] = *(const short8*)(bBase + (bRow0 + cf*16 + llo) * 128 + koff);
      __builtin_amdgcn_s_setprio(1);
      #pragma unroll
      for (int rf = 0; rf < 4; ++rf)
        #pragma unroll
        for (int cf = 0; cf < 4; ++cf)
          acc[rf][cf] = __builtin_amdgcn_mfma_f32_16x16x32_bf16(
              ar[rf], br[cf], acc[rf][cf], 0, 0, 0);
      __builtin_amdgcn_s_setprio(0);
    }
    blockbar();
    if (t + 1 < NT) { stage(0, t + 1); stage(1, t + 1); stage(2, t + 1); }
  }

  // epilogue: exp -> bf16 P stores (no rowsum)
  #pragma unroll
  for (int rf = 0; rf < 4; ++rf) {
    float e[4][4];
    #pragma unroll
    for (int cf = 0; cf < 4; ++cf)
      #pragma unroll
      for (int j = 0; j < 4; ++j)
        e[cf][j] = __expf(acc[rf][cf][j]);
    #pragma unroll
    for (int j = 0; j < 4; ++j) {
      const size_t m = m0 + wm*64 + rf*16 + lhi*4 + j;
      #pragma unroll
      for (int cf = 0; cf < 4; ++cf) {
        const size_t n = n0 + wn*64 + cf*16 + llo;
        Pout[m * (size_t)ldC + n] = f2bf(e[cf][j]);
      }
    }
  }
}

// ================= GEMM2: 256x256 pipelined (R18-verbatim, EPI=1 path) =================
// Accumulates acc_rs[rf] = sum_k A[m][k] via ones-MFMA (lane-local divisor),
// Oout = acc / acc_rs.
template <int EPI>
__global__ __launch_bounds__(512, 2) void gemm_bt(
    const ushort* __restrict__ A, const ushort* __restrict__ B,
    int aStride, int bStride,      // row strides in BYTES
    int NT,                        // K / 64
    ushort* __restrict__ Pout, float* __restrict__ Oout,
    int ldC)                       // C row stride in ELEMENTS
{
  __shared__ ushort lds[2][4][8192];   // [buf][slot:A0,A1,B0,B1][16KB]
  char* ldsb = (char*)&lds[0][0][0];

  const int tid = threadIdx.x;
  const int w   = tid >> 6;
  const int l   = tid & 63;
  const int lhi = l >> 4;
  const int llo = l & 15;
  const int wm  = w >> 2;        // 0..1
  const int wn  = w & 3;         // 0..3
  const size_t m0 = (size_t)blockIdx.x * 256;
  const size_t n0 = (size_t)blockIdx.y * 256;

  const char* Ab = (const char*)A;
  const char* Bb = (const char*)B;

  const int srow = tid >> 3;           // 0..63
  const int scb  = (tid & 7) * 16;     // 0..112
  auto stage = [&](int buf, int slot, int t) {
    const char* src; int stride; size_t r0;
    if (slot < 2) { src = Ab; stride = aStride; r0 = m0 + (size_t)slot * 128; }
    else          { src = Bb; stride = bStride; r0 = n0 + (size_t)(slot - 2) * 128; }
    char* lbase = ldsb + ((buf*4 + slot) * 16384) + w * 1024;   // wave-uniform
    {
      const int row = srow;
      const char* g = src + (r0 + row) * (size_t)stride + t*128 + (scb ^ ((row & 7) << 4));
      __builtin_amdgcn_global_load_lds(GLP(g), LDP(lbase), 16, 0, 0);
    }
    {
      const int row = srow + 64;
      const char* g = src + (r0 + row) * (size_t)stride + t*128 + (scb ^ ((row & 7) << 4));
      __builtin_amdgcn_global_load_lds(GLP(g), LDP(lbase + 8192), 16, 0, 0);
    }
  };

  const unsigned swz = (unsigned)((l & 7) << 4);
  short8 ar[4][2], br01[2][2], br23[2][2];
  f32x4 acc[8][4] = {};
  f32x4 acc_rs[8] = {};                // rowsum accumulator (EPI==1)
  short8 ones;
  #pragma unroll
  for (int i = 0; i < 8; ++i) ones[i] = (short)0x3F80;   // bf16 1.0

  const char* aBase0 = ldsb + wm * 16384;
  const char* bBase0 = ldsb + (2 + (wn >> 1)) * 16384;
  const unsigned bRow0 = (unsigned)((wn & 1) * 64);

  auto readA = [&](int buf, int rfB) {
    const char* base = aBase0 + buf * 65536;
    #pragma unroll
    for (int rf = 0; rf < 4; ++rf)
      #pragma unroll
      for (int kk = 0; kk < 2; ++kk) {
        unsigned off = (unsigned)(((rfB + rf) * 16 + llo) * 128)
                     + (((unsigned)(kk*64 + lhi*16)) ^ swz);
        ar[rf][kk] = *(const short8*)(base + off);
      }
  };
  auto readB = [&](int buf, int cfB, short8 (&br)[2][2]) {
    const char* base = bBase0 + buf * 65536;
    #pragma unroll
    for (int c = 0; c < 2; ++c)
      #pragma unroll
      for (int kk = 0; kk < 2; ++kk) {
        unsigned off = (unsigned)((bRow0 + (cfB + c) * 16 + llo) * 128)
                     + (((unsigned)(kk*64 + lhi*16)) ^ swz);
        br[c][kk] = *(const short8*)(base + off);
      }
  };
  auto quad = [&](int rfB, int cfB, short8 (&br)[2][2]) {
    __builtin_amdgcn_s_setprio(1);
    #pragma unroll
    for (int kk = 0; kk < 2; ++kk) {
      #pragma unroll
      for (int rf = 0; rf < 4; ++rf) {
        #pragma unroll
        for (int c = 0; c < 2; ++c)
          acc[rfB+rf][cfB+c] = __builtin_amdgcn_mfma_f32_16x16x32_bf16(
              ar[rf][kk], br[c][kk], acc[rfB+rf][cfB+c], 0, 0, 0);
        if (EPI == 1 && cfB == 0)
          acc_rs[rfB+rf] = __builtin_amdgcn_mfma_f32_16x16x32_bf16(
              ar[rf][kk], ones, acc_rs[rfB+rf], 0, 0, 0);
      }
    }
    __builtin_amdgcn_s_setprio(0);
  };

  // prologue: B0(0),A0(0),A1(0),B1(0),B0(1),A0(1)
  stage(0, 2, 0); stage(0, 0, 0); stage(0, 1, 0); stage(0, 3, 0);
  stage(1, 2, 1); stage(1, 0, 1);

  for (int t = 0; t < NT; ++t) {
    const int cur = t & 1, nxt = cur ^ 1;
    // ph1
    if (t + 1 < NT) asm volatile("s_waitcnt vmcnt(4)" ::: "memory");
    else            asm volatile("s_waitcnt vmcnt(0)" ::: "memory");
    blockbar();
    readA(cur, 0);
    readB(cur, 0, br01);
    if (t + 1 < NT) stage(nxt, 1, t + 1);
    quad(0, 0, br01);
    // ph2
    blockbar();
    readB(cur, 2, br23);
    if (t + 1 < NT) stage(nxt, 3, t + 1);
    quad(0, 2, br23);
    // ph3
    blockbar();
    readA(cur, 4);
    if (t + 2 < NT) stage(cur, 2, t + 2);
    quad(4, 2, br23);
    // ph4
    blockbar();
    if (t + 2 < NT) stage(cur, 0, t + 2);
    quad(4, 0, br01);
  }

  // ---- epilogue ----
  if (EPI == 0) {
    #pragma unroll
    for (int rf = 0; rf < 8; ++rf) {
      float e[4][4];
      #pragma unroll
      for (int cf = 0; cf < 4; ++cf)
        #pragma unroll
        for (int j = 0; j < 4; ++j)
          e[cf][j] = __expf(acc[rf][cf][j]);
      #pragma unroll
      for (int j = 0; j < 4; ++j) {
        const size_t m = m0 + wm*128 + rf*16 + lhi*4 + j;
        #pragma unroll
        for (int cf = 0; cf < 4; ++cf) {
          const size_t n = n0 + wn*64 + cf*16 + llo;
          Pout[m * (size_t)ldC + n] = f2bf(e[cf][j]);
        }
      }
    }
  } else {
    #pragma unroll
    for (int rf = 0; rf < 8; ++rf)
      #pragma unroll
      for (int j = 0; j < 4; ++j) {
        const size_t m = m0 + wm*128 + rf*16 + lhi*4 + j;
        const float inv = 1.0f / acc_rs[rf][j];
        #pragma unroll
        for (int cf = 0; cf < 4; ++cf) {
          const size_t n = n0 + wn*64 + cf*16 + llo;
          Oout[m * (size_t)ldC + n] = acc[rf][cf][j] * inv;
        }
      }
  }
}

// ================= fallback: R7 fused kernel (proven, ~586us) =================
constexpr int BMf = 64, BHf = 256, NHf = S_DIM / BHf, NWf = 8;
constexpr int PBUFf = BMf * BHf * 2;

__global__ __launch_bounds__(512, 2) void attn_fused(
    const float* __restrict__ Q, const ushort* __restrict__ Kn,
    const ushort* __restrict__ Vt, float* __restrict__ out)
{
  __shared__ ushort q_s[BMf * D_DIM];
  __shared__ ushort p_s[2 * BMf * BHf];
  __shared__ float  rs_lds[NWf * BMf];
  __shared__ float  rs_tot[BMf];
  char* qb = (char*)q_s;
  char* pb = (char*)p_s;
  const int tid = threadIdx.x;
  const int w   = tid >> 6;
  const int l   = tid & 63;
  const int lhi = l >> 4;
  const int llo = l & 15;
  const size_t q0 = (size_t)blockIdx.x * BMf;
  {
    const int row = tid >> 3;
    const int c   = tid & 7;
    const unsigned swzr = (unsigned)((row & 7) << 4);
    const float4* src = (const float4*)(Q + (q0 + row) * D_DIM);
    float4 t[16];
    float ss = 0.f;
    #pragma unroll
    for (int i = 0; i < 16; ++i) {
      t[i] = src[c + i*8];
      ss += t[i].x*t[i].x + t[i].y*t[i].y + t[i].z*t[i].z + t[i].w*t[i].w;
    }
    ss += __shfl_xor(ss, 1, 64);
    ss += __shfl_xor(ss, 2, 64);
    ss += __shfl_xor(ss, 4, 64);
    const float sc = 1.0f / fmaxf(sqrtf(ss), 1e-12f);
    #pragma unroll
    for (int i = 0; i < 16; ++i) {
      u32x2 pv;
      pv[0] = (unsigned)f2bf(t[i].x*sc) | ((unsigned)f2bf(t[i].y*sc) << 16);
      pv[1] = (unsigned)f2bf(t[i].z*sc) | ((unsigned)f2bf(t[i].w*sc) << 16);
      unsigned byte = (unsigned)(row*1024) + (((unsigned)(c*8 + i*64)) ^ swzr);
      *(u32x2*)(qb + byte) = pv;
    }
  }
  __syncthreads();
  f32x4 o[4][4] = {};
  float rs_acc[4] = {0.f, 0.f, 0.f, 0.f};
  const unsigned swz = (unsigned)((l & 7) << 4);
  unsigned rowbQ[4], rowbP[4];
  #pragma unroll
  for (int qf = 0; qf < 4; ++qf) {
    rowbQ[qf] = (unsigned)((qf*16 + llo) * 1024);
    rowbP[qf] = (unsigned)((qf*16 + llo) * 512);
  }
  auto do_qkt = [&](int h, f32x4 (&sacc)[2][4]) {
    const short8* kp[2];
    #pragma unroll
    for (int kf = 0; kf < 2; ++kf)
      kp[kf] = (const short8*)(Kn + (size_t)(h*BHf + w*32 + kf*16 + llo) * D_DIM + lhi*8);
    __builtin_amdgcn_s_setprio(1);
    #pragma unroll
    for (int ks = 0; ks < 16; ++ks) {
      const unsigned off = ((unsigned)(ks*64 + lhi*16)) ^ swz;
      short8 a[2], b[4];
      #pragma unroll
      for (int kf = 0; kf < 2; ++kf) a[kf] = kp[kf][ks*4];
      #pragma unroll
      for (int qf = 0; qf < 4; ++qf)
        b[qf] = *(const short8*)(qb + (rowbQ[qf] + off));
      #pragma unroll
      for (int kf = 0; kf < 2; ++kf)
        #pragma unroll
        for (int qf = 0; qf < 4; ++qf)
          sacc[kf][qf] = __builtin_amdgcn_mfma_f32_16x16x32_bf16(a[kf], b[qf], sacc[kf][qf], 0, 0, 0);
    }
    __builtin_amdgcn_s_setprio(0);
  };
  auto do_exp = [&](f32x4 (&sacc)[2][4], u32x2 (&pk)[2][4]) {
    #pragma unroll
    for (int kf = 0; kf < 2; ++kf)
      #pragma unroll
      for (int qf = 0; qf < 4; ++qf) {
        float p0 = __expf(sacc[kf][qf][0]);
        float p1 = __expf(sacc[kf][qf][1]);
        float p2 = __expf(sacc[kf][qf][2]);
        float p3 = __expf(sacc[kf][qf][3]);
        rs_acc[qf] += (p0 + p1) + (p2 + p3);
        pk[kf][qf][0] = (unsigned)f2bf(p0) | ((unsigned)f2bf(p1) << 16);
        pk[kf][qf][1] = (unsigned)f2bf(p2) | ((unsigned)f2bf(p3) << 16);
      }
  };
  auto do_pwrite = [&](u32x2 (&pk)[2][4], char* buf) {
    #pragma unroll
    for (int kf = 0; kf < 2; ++kf)
      #pragma unroll
      for (int qf = 0; qf < 4; ++qf) {
        unsigned lin = (unsigned)(w*64 + kf*32 + lhi*8);
        *(u32x2*)(buf + rowbP[qf] + (lin ^ swz)) = pk[kf][qf];
      }
  };
  auto do_pv = [&](int h, const char* buf) {
    const short8* vp[4];
    #pragma unroll
    for (int df = 0; df < 4; ++df)
      vp[df] = (const short8*)(Vt + (size_t)(w*64 + df*16 + llo) * S_DIM + h*BHf + lhi*8);
    __builtin_amdgcn_s_setprio(1);
    #pragma unroll
    for (int ks = 0; ks < 8; ++ks) {
      const unsigned off = ((unsigned)(ks*64 + lhi*16)) ^ swz;
      short8 a[4], b[4];
      #pragma unroll
      for (int qf = 0; qf < 4; ++qf)
        a[qf] = *(const short8*)(buf + (rowbP[qf] + off));
      #pragma unroll
      for (int df = 0; df < 4; ++df) b[df] = vp[df][ks*4];
      #pragma unroll
      for (int qf = 0; qf < 4; ++qf)
        #pragma unroll
        for (int df = 0; df < 4; ++df)
          o[qf][df] = __builtin_amdgcn_mfma_f32_16x16x32_bf16(a[qf], b[df], o[qf][df], 0, 0, 0);
    }
    __builtin_amdgcn_s_setprio(0);
  };
  {
    f32x4 sacc[2][4] = {};
    do_qkt(0, sacc);
    u32x2 pk[2][4];
    do_exp(sacc, pk);
    do_pwrite(pk, pb + 0);
  }
  __syncthreads();
  for (int i = 0; i < NHf - 1; ++i) {
    f32x4 sacc[2][4] = {};
    do_qkt(i + 1, sacc);
    u32x2 pk[2][4];
    do_exp(sacc, pk);
    do_pv(i, pb + (i & 1) * PBUFf);
    do_pwrite(pk, pb + ((i + 1) & 1) * PBUFf);
    __syncthreads();
  }
  do_pv(NHf - 1, pb + ((NHf - 1) & 1) * PBUFf);
  #pragma unroll
  for (int qf = 0; qf < 4; ++qf) {
    float v = rs_acc[qf];
    v += __shfl_xor(v, 16, 64);
    v += __shfl_xor(v, 32, 64);
    if (l < 16) rs_lds[w*BMf + qf*16 + llo] = v;
  }
  __syncthreads();
  if (tid < BMf) {
    float tot = 0.f;
    #pragma unroll
    for (int ww = 0; ww < NWf; ++ww) tot += rs_lds[ww*BMf + tid];
    rs_tot[tid] = tot;
  }
  __syncthreads();
  #pragma unroll
  for (int qf = 0; qf < 4; ++qf)
    #pragma unroll
    for (int r = 0; r < 4; ++r) {
      const int query = qf*16 + lhi*4 + r;
      const float inv = 1.0f / rs_tot[query];
      #pragma unroll
      for (int df = 0; df < 4; ++df) {
        const int dim = w*64 + df*16 + llo;
        out[(q0 + query) * D_DIM + dim] = o[qf][df][r] * inv;
      }
    }
}

extern "C" void kernel_launch(void* const* d_in, const int* in_sizes, int n_in,
                              void* d_out, int out_size, void* d_ws, size_t ws_size,
                              hipStream_t stream) {
  const float* Q = (const float*)d_in[0];
  const float* K = (const float*)d_in[1];
  const float* V = (const float*)d_in[2];
  float* out = (float*)d_out;
  const int N = in_sizes[0] / D_DIM;          // 65536

  ushort* Kn = (ushort*)d_ws;                                // [S][D] bf16, 2MB
  ushort* Vt = Kn + (size_t)S_DIM * D_DIM;                   // [D][S] bf16, 2MB
  char*   rest = (char*)(Vt + (size_t)D_DIM * S_DIM);
  const size_t base_bytes = (size_t)S_DIM * D_DIM * 2 * 2;   // 4MB
  const size_t avail = ws_size > base_bytes ? ws_size - base_bytes : 0;

  // bytes per chunk-row: Qn (D*2) + P (S*2). Cap chunk at 32768 so P (<=128MB)
  // stays L3-resident for GEMM2 (65536 spills: R13/R14 evidence).
  const size_t perRow = (size_t)D_DIM*2 + (size_t)S_DIM*2;
  int chunk = 0;
  const int cand[4] = {32768, 16384, 8192, 4096};
  for (int i = 0; i < 4; ++i)
    if ((size_t)cand[i] * perRow <= avail && (N % cand[i]) == 0) { chunk = cand[i]; break; }

  k_norm<<<S_DIM/4, 256, 0, stream>>>(K, Kn);
  k_transpose_v<<<dim3(S_DIM/64, D_DIM/64), 256, 0, stream>>>(V, Vt);

  if (chunk == 0) {
    attn_fused<<<N/BMf, 512, 0, stream>>>(Q, Kn, Vt, out);
    return;
  }

  ushort* Qn = (ushort*)rest;                                 // [chunk][D]
  ushort* P  = Qn + (size_t)chunk * D_DIM;                    // [chunk][S]

  for (int c = 0; c < N; c += chunk) {
    k_norm<<<chunk/4, 256, 0, stream>>>(Q + (size_t)c * D_DIM, Qn);
    // GEMM1: P = exp(Qn * Kn^T) -- 128x256 single-buffer, 2 blocks/CU
    gemm1_sb<<<dim3(chunk/128, S_DIM/256), 512, 0, stream>>>(
        Qn, Kn, D_DIM*2, D_DIM*2, D_DIM/64, P, S_DIM);
    // GEMM2: out = (P * Vt^T) / rowsum, rowsum via lane-local ones-MFMA
    gemm_bt<1><<<dim3(chunk/256, D_DIM/256), 512, 0, stream>>>(
        P, Vt, S_DIM*2, S_DIM*2, S_DIM/64, nullptr,
        out + (size_t)c * D_DIM, D_DIM);
  }
}